// Round 9
// baseline (341.059 us; speedup 1.0000x reference)
//
#include <hip/hip_runtime.h>
#include <math.h>

#define B_    4
#define T_    8192
#define C_    1024
#define E_    64
#define NTOK  (B_*T_)          // 32768
#define KSEL  2

// d_out offsets (in floats): idx, scores, probs, importance, load
#define OFF_IDX    0
#define OFF_SCORES (NTOK*KSEL)               // 65536
#define OFF_PROBS  (2*NTOK*KSEL)             // 131072
#define OFF_IMP    (OFF_PROBS + NTOK*E_)     // 2228224
#define OFF_LOAD   (OFF_IMP + E_)            // 2228288

// workspace offsets (bytes)
#define WS_W32    0                          // 1024*64*4 = 256 KB ([d][e], refine)
#define WS_BSWH   262144                     // 128 KB bf16 hi, MFMA-frag order
#define WS_BSWL   393216                     // 128 KB bf16 lo
#define WS_LB64   524288                     // 4*64*8 = 2 KB  (zeroed w/ CNT)
#define WS_CNT    526336                     // 4
#define WS_LIST   526400                     // REFINE_CAP*4 = 32 KB
#define WS_IMPP   559168                     // 512*64*4 = 128 KB importance partials
#define WS_CNTP   690240                     // 512*64*4 = 128 KB count partials

#define REFINE_CAP 8192
#define REFINE_EPS 3e-4f

typedef __attribute__((ext_vector_type(8))) short short8;
typedef __attribute__((ext_vector_type(4))) float f32x4;

// raw workgroup barrier (no vmcnt/lgkm drain), fenced against compiler motion
#define BAR() do { asm volatile("" ::: "memory"); \
                   __builtin_amdgcn_s_barrier();  \
                   asm volatile("" ::: "memory"); } while (0)

// binding global load: compiler CANNOT sink/serialize these (R2 failure mode)
#define GL0(dst, p)    asm volatile("global_load_dwordx4 %0, %1, off" \
                                    : "=v"(dst) : "v"(p) : "memory")

// ---------------------------------------------------------------------------
// K_prep: v9 change = wg_s padded to stride 65. Old layout wg_s[(c4+j)*64+r]
// put all 64 lanes' stores into banks r&31 (4 banks) = 16-way conflict x 16
// stores x 16 chunks. Stride 65: bank = (4a+j+r)&31 with (a,r) bijective onto
// 0..63 -> exactly 2 lanes/bank = free. Read wg_s[c*65+e]: bank (c+e)&31,
// 2 lanes/bank = free. fp64 math and everything else unchanged.
// ---------------------------------------------------------------------------
__global__ __launch_bounds__(256) void k_prep(const float* __restrict__ Wg,
                                              const float* __restrict__ Wc,
                                              const float* __restrict__ cond,
                                              float* __restrict__ wcomb32,
                                              short* __restrict__ bswH,
                                              short* __restrict__ bswL,
                                              double* __restrict__ lbias64,
                                              float* __restrict__ out) {
    __shared__ float wg_s[64 * 65];   // [c][e] padded (bank-conflict-free)
    __shared__ float wc_s[64 * 4];    // [c][d_local]
    __shared__ double red[256];

    const int tid = threadIdx.x;
    const int e   = tid & 63;
    const int dg  = tid >> 6;                  // 0..3
    const int d0  = blockIdx.x * 4;

    if (blockIdx.x == 0 && tid < 2 * E_) out[OFF_IMP + tid] = 0.f;

    double ae = 0.0, ao = 0.0;                 // even / odd c chains

    for (int c0 = 0; c0 < C_; c0 += 64) {
        __syncthreads();
#pragma unroll
        for (int k = 0; k < 4; ++k) {
            int li = tid + k * 256;
            int r = li >> 4, c4 = (li & 15) * 4;
            float4 v = *(const float4*)&Wg[(size_t)r * 1024 + c0 + c4];
            wg_s[(c4 + 0) * 65 + r] = v.x;
            wg_s[(c4 + 1) * 65 + r] = v.y;
            wg_s[(c4 + 2) * 65 + r] = v.z;
            wg_s[(c4 + 3) * 65 + r] = v.w;
        }
        if (tid < 128) {
            int cc = tid >> 1, dd0 = (tid & 1) * 2;
            *(float2*)&wc_s[cc * 4 + dd0] =
                *(const float2*)&Wc[(size_t)(c0 + cc) * 2048 + d0 + dd0];
        }
        __syncthreads();
#pragma unroll 8
        for (int c = 0; c < 64; c += 2) {
            ae += (double)wg_s[(c + 0) * 65 + e] * (double)wc_s[(c + 0) * 4 + dg];
            ao += (double)wg_s[(c + 1) * 65 + e] * (double)wc_s[(c + 1) * 4 + dg];
        }
    }
    const double acc = ae + ao;

    if (d0 < 1024) {
        const int d = d0 + dg;
        const int et = e >> 4, nn = e & 15;
        float f = (float)acc;
        wcomb32[d * 64 + e] = f;
        unsigned u = __float_as_uint(f);
        short hi = (short)(u >> 16);
        float r = f - __uint_as_float(u & 0xFFFF0000u);
        short lo = (short)(__float_as_uint(r) >> 16);
        int kchunk = d >> 5, qsel = (d >> 3) & 3, j = d & 7;
        int idx = ((kchunk * 4 + et) * 64 + qsel * 16 + nn) * 8 + j;
        bswH[idx] = hi;
        bswL[idx] = lo;
    } else {
        const int da = d0 - 1024 + dg;
#pragma unroll
        for (int b = 0; b < 4; ++b) {
            double pb = (double)cond[b * 1024 + da] * acc;
            __syncthreads();
            red[tid] = pb;
            __syncthreads();
            if (tid < 64) {
                double s = red[tid] + red[tid + 64] + red[tid + 128] + red[tid + 192];
#if __has_builtin(__builtin_amdgcn_global_atomic_fadd_f64)
                unsafeAtomicAdd(&lbias64[b * 64 + tid], s);
#else
                atomicAdd(&lbias64[b * 64 + tid], s);
#endif
            }
        }
    }
}

// ---------------------------------------------------------------------------
// split 8 consecutive fp32 into bf16 hi + lo
// ---------------------------------------------------------------------------
__device__ __forceinline__ void split8(const float* xv, short8& h, short8& l) {
#pragma unroll
    for (int j = 0; j < 8; ++j) {
        unsigned u = __float_as_uint(xv[j]);
        h[j] = (short)(u >> 16);
        float r = xv[j] - __uint_as_float(u & 0xFFFF0000u);
        l[j] = (short)(__float_as_uint(r) >> 16);
    }
}

// ---------------------------------------------------------------------------
// K_main v9: K-loop byte-identical to v8 (B-amortized expert-quarter waves,
// DMA+XOR-swizzled A, counted vmcnt). ONE change: the 128 chip-serialized
// global fp32 atomicAdds per block (importance + load, all blocks hammering
// the SAME 64+64 floats -> 65k RMW ops through 2-4 L2 cache lines, a
// dispatch-retire tail invisible to pipe counters) are replaced with plain
// per-block partial stores; k_stats reduces them. Per-block arithmetic
// identical; MFMA path untouched -> absmax unchanged.
// ---------------------------------------------------------------------------
#define MT    64
#define ROWP  65          // epilogue logits row stride (aliases buf0)

__device__ __forceinline__ void stage_tile(const float* __restrict__ x,
                                           float* xs, int token0, int t,
                                           int buf, int wid, int lane) {
#pragma unroll
    for (int p = 0; p < 8; ++p) {
        const int sbase = p * 256 + wid * 64;      // wave-uniform 16B-slot base
        const int s  = sbase + lane;
        const int r  = s >> 5;                     // row 0..63
        const int f  = (s & 31) ^ (r & 7);         // logical 16B granule
        const float* g = &x[(size_t)(token0 + r) * 1024 + t * 128 + f * 4];
        float* l = xs + buf * 8192 + sbase * 4;    // linear dest; HW adds lane*16B
        __builtin_amdgcn_global_load_lds(
            (const __attribute__((address_space(1))) unsigned int*)g,
            (__attribute__((address_space(3))) unsigned int*)l, 16, 0, 0);
    }
}

__global__ __launch_bounds__(256, 2) void k_main(const float* __restrict__ x,
                                                 const short* __restrict__ bswH,
                                                 const short* __restrict__ bswL,
                                                 const double* __restrict__ lbias64,
                                                 float* __restrict__ out,
                                                 unsigned int* __restrict__ ref_cnt,
                                                 int* __restrict__ ref_list,
                                                 float* __restrict__ imp_part,
                                                 float* __restrict__ cnt_part) {
    __shared__ __align__(16) float xs[2 * 8192];  // 64 KB: 2 tile buffers; buf0 reused as logits
    __shared__ float invs[MT];
    __shared__ unsigned int cnts[E_];

    const int tid    = threadIdx.x;
    const int wid    = tid >> 6;                  // = expert quarter (et)
    const int lane   = tid & 63;
    const int nn     = lane & 15;
    const int qsel   = lane >> 4;
    const int token0 = blockIdx.x * MT;
    const int b      = token0 >> 13;              // /8192

    if (tid < E_) cnts[tid] = 0;

    f32x4 acc[4];                                 // 4 token-groups x 16 experts
#pragma unroll
    for (int g = 0; g < 4; ++g) acc[g] = (f32x4){0.f, 0.f, 0.f, 0.f};

    // byte base of this wave's B fragments: slab (kchunk*4 + wid), lane*16 B
    const char* bh0 = (const char*)bswH + (size_t)wid * 1024 + lane * 16;
    const char* bl0 = (const char*)bswL + (size_t)wid * 1024 + lane * 16;

    // ---- prologue: stage tile 0 ----
    stage_tile(x, xs, token0, 0, 0, wid, lane);

    for (int t = 0; t < 8; ++t) {                 // K-tiles of 128
        const int cur = t & 1;

        // ---- binding B batch: this wave's 8 fragments of tile t ----
        short8 Bh[4], Bl[4];
        {
            const char* ph = bh0 + (size_t)t * 16384;
            const char* pl = bl0 + (size_t)t * 16384;
#pragma unroll
            for (int kc = 0; kc < 4; ++kc) {
                GL0(Bh[kc], ph + kc * 4096);
                GL0(Bl[kc], pl + kc * 4096);
            }
        }
        // ---- issue next A-tile DMA (flies across compute of t) ----
        if (t < 7) stage_tile(x, xs, token0, t + 1, cur ^ 1, wid, lane);
        // ---- wait: B(t)[8] + stage(t)[8] done; stage(t+1)[8] in flight ----
        if (t < 7) asm volatile("s_waitcnt vmcnt(8)" ::: "memory");
        else       asm volatile("s_waitcnt vmcnt(0)" ::: "memory");
        __builtin_amdgcn_sched_barrier(0);        // rule #18: nothing crosses the wait
        BAR();                                     // all waves' tile-t A landed

        // ---- compute: 4 kc x 4 token-groups, B reused across 64 tokens ----
        const float* abase = xs + cur * 8192;
#pragma unroll
        for (int kc = 0; kc < 4; ++kc) {
            const int f0 = kc * 8 + qsel * 2;
            short8 ah[4], al[4];
#pragma unroll
            for (int g = 0; g < 4; ++g) {
                const int rr = g * 16 + nn;
                const int rx = rr & 7;
                float xv[8];
                *(f32x4*)&xv[0] = *(const f32x4*)(abase + rr * 128 + (((f0    ) ^ rx) << 2));
                *(f32x4*)&xv[4] = *(const f32x4*)(abase + rr * 128 + (((f0 + 1) ^ rx) << 2));
                split8(xv, ah[g], al[g]);
            }
#pragma unroll
            for (int g = 0; g < 4; ++g) {
                acc[g] = __builtin_amdgcn_mfma_f32_16x16x32_bf16(ah[g], Bh[kc], acc[g], 0, 0, 0);
                acc[g] = __builtin_amdgcn_mfma_f32_16x16x32_bf16(ah[g], Bl[kc], acc[g], 0, 0, 0);
                acc[g] = __builtin_amdgcn_mfma_f32_16x16x32_bf16(al[g], Bh[kc], acc[g], 0, 0, 0);
            }
        }
        BAR();                                     // all waves done reading buf[cur]
    }

    // ---- epilogue: logits into xs[tok][e] (stride ROWP, aliases buf0) ----
    const int q4 = qsel * 4;
    {
        float lb = (float)lbias64[b * 64 + wid * 16 + nn];
#pragma unroll
        for (int g = 0; g < 4; ++g) {
#pragma unroll
            for (int r = 0; r < 4; ++r) {
                int tok = g * 16 + q4 + r;
                xs[tok * ROWP + wid * 16 + nn] = acc[g][r] + lb;
            }
        }
    }
    __syncthreads();

    if (tid < MT) {
        const int tk = tid;
        const int base = tk * ROWP;
        float v1 = -1e30f, v2 = -1e30f, v3 = -1e30f;
        int i1 = 0, i2 = 0;
        for (int e = 0; e < E_; ++e) {
            float l = xs[base + e];
            if (l > v1)      { v3 = v2; v2 = v1; i2 = i1; v1 = l; i1 = e; }
            else if (l > v2) { v3 = v2; v2 = l; i2 = e; }
            else if (l > v3) { v3 = l; }
        }
        float sum = 0.f;
        for (int e = 0; e < E_; ++e) {
            float ex = __expf(xs[base + e] - v1);
            xs[base + e] = ex;
            sum += ex;
        }
        invs[tk] = 1.0f / sum;

        const int gt = token0 + tk;
        float s1 = 1.0f / (1.0f + __expf(v2 - v1));   // softmax over top-2
        *(float2*)&out[OFF_IDX + (size_t)gt * 2]    = make_float2((float)i1, (float)i2);
        *(float2*)&out[OFF_SCORES + (size_t)gt * 2] = make_float2(s1, 1.0f - s1);
        atomicAdd(&cnts[i1], 1u);
        atomicAdd(&cnts[i2], 1u);

        float g12 = v1 - v2, g23 = v2 - v3;
        float g = g12 < g23 ? g12 : g23;
        if (g < REFINE_EPS) {
            unsigned int pos = atomicAdd(ref_cnt, 1u);
            if (pos < REFINE_CAP) ref_list[pos] = gt;
        }
    }
    __syncthreads();

    // probs: 4096 floats = 1024 float4, coalesced (4 per thread)
    float* probs = out + OFF_PROBS + (size_t)token0 * E_;
#pragma unroll
    for (int k = 0; k < 4; ++k) {
        int li4 = tid + k * 256;
        int tok = li4 >> 4;
        int c4 = (li4 & 15) << 2;
        float inv = invs[tok];
        int o = tok * ROWP + c4;
        *(float4*)&probs[(size_t)li4 * 4] =
            make_float4(xs[o] * inv, xs[o + 1] * inv,
                        xs[o + 2] * inv, xs[o + 3] * inv);
    }

    // importance + load: PLAIN per-block partial stores (no global atomics)
    if (tid < E_) {
        const int e = tid;
        float s = 0.f;
        for (int tt = 0; tt < MT; ++tt) s += xs[tt * ROWP + e] * invs[tt];
        imp_part[blockIdx.x * 64 + e] = s;
        cnt_part[blockIdx.x * 64 + e] = (float)cnts[e];
    }
}

// ---------------------------------------------------------------------------
// K_stats: reduce 512x64 partials -> importance, load. 2 blocks x 256 thr;
// block 0 = importance, block 1 = load. Thread (q=tid>>6, e=tid&63) sums
// rows q,q+4,... (coalesced across e); LDS tree over q; plain stores.
// ---------------------------------------------------------------------------
__global__ __launch_bounds__(256) void k_stats(const float* __restrict__ imp_part,
                                               const float* __restrict__ cnt_part,
                                               float* __restrict__ out) {
    __shared__ float red[256];
    const int tid = threadIdx.x;
    const int q = tid >> 6, e = tid & 63;
    const float* src = (blockIdx.x == 0) ? imp_part : cnt_part;
    float s = 0.f;
    for (int r = q; r < 512; r += 4)
        s += src[r * 64 + e];
    red[tid] = s;
    __syncthreads();
    if (tid < 64) {
        float t = red[e] + red[64 + e] + red[128 + e] + red[192 + e];
        if (blockIdx.x == 0) out[OFF_IMP + e]  = t * (1.0f / (float)NTOK);
        else                 out[OFF_LOAD + e] = t * (1.0f / (float)(NTOK * KSEL));
    }
}

// ---------------------------------------------------------------------------
// K_ref: UNCHANGED. fp64 re-evaluation of ambiguous tokens, one wave/token.
// ---------------------------------------------------------------------------
__global__ __launch_bounds__(256) void k_refine(const float* __restrict__ x,
                                                const float* __restrict__ wcomb32,
                                                const double* __restrict__ lbias64,
                                                const unsigned int* __restrict__ ref_cnt,
                                                const int* __restrict__ ref_list,
                                                float* __restrict__ out) {
    int wave = (int)((blockIdx.x * blockDim.x + threadIdx.x) >> 6);
    int lane = threadIdx.x & 63;
    unsigned int n = *ref_cnt;
    if (n > REFINE_CAP) n = REFINE_CAP;
    const int nwaves = (int)((gridDim.x * blockDim.x) >> 6);

    for (unsigned int wi = wave; wi < n; wi += nwaves) {
        const int gt = ref_list[wi];
        const int b = gt / T_;
        const float* xrow = x + (size_t)gt * C_;
        double a0 = 0.0, a1 = 0.0, a2 = 0.0, a3 = 0.0;
        for (int d = 0; d < C_; d += 4) {
            a0 += (double)xrow[d + 0] * (double)wcomb32[(d + 0) * 64 + lane];
            a1 += (double)xrow[d + 1] * (double)wcomb32[(d + 1) * 64 + lane];
            a2 += (double)xrow[d + 2] * (double)wcomb32[(d + 2) * 64 + lane];
            a3 += (double)xrow[d + 3] * (double)wcomb32[(d + 3) * 64 + lane];
        }
        double acc = ((a0 + a1) + (a2 + a3)) + lbias64[b * 64 + lane];

        double v = acc; int id = lane;
        for (int off = 32; off > 0; off >>= 1) {
            double ov = __shfl_xor(v, off, 64);
            int oid   = __shfl_xor(id, off, 64);
            if (ov > v || (ov == v && oid < id)) { v = ov; id = oid; }
        }
        double v1 = v; int i1 = id;
        v = (lane == i1) ? -1e300 : acc; id = lane;
        for (int off = 32; off > 0; off >>= 1) {
            double ov = __shfl_xor(v, off, 64);
            int oid   = __shfl_xor(id, off, 64);
            if (ov > v || (ov == v && oid < id)) { v = ov; id = oid; }
        }
        double v2 = v; int i2 = id;

        if (lane == 0) {
            float s1 = (float)(1.0 / (1.0 + exp(v2 - v1)));
            *(float2*)&out[OFF_IDX + (size_t)gt * 2]    = make_float2((float)i1, (float)i2);
            *(float2*)&out[OFF_SCORES + (size_t)gt * 2] = make_float2(s1, 1.0f - s1);
        }
    }
}

// ---------------------------------------------------------------------------
extern "C" void kernel_launch(void* const* d_in, const int* in_sizes, int n_in,
                              void* d_out, int out_size, void* d_ws, size_t ws_size,
                              hipStream_t stream) {
    const float* x    = (const float*)d_in[0];   // (4,8192,1024)
    const float* cond = (const float*)d_in[1];   // (4,1024)
    const float* Wg   = (const float*)d_in[2];   // (64,1024)
    const float* Wc   = (const float*)d_in[3];   // (1024,2048)
    float* out = (float*)d_out;
    char*  ws  = (char*)d_ws;

    float*  wcomb32 = (float*)(ws + WS_W32);
    short*  bswH    = (short*)(ws + WS_BSWH);
    short*  bswL    = (short*)(ws + WS_BSWL);
    double* lbias64 = (double*)(ws + WS_LB64);
    unsigned int* ref_cnt = (unsigned int*)(ws + WS_CNT);
    int*    ref_list = (int*)(ws + WS_LIST);
    float*  imp_part = (float*)(ws + WS_IMPP);
    float*  cnt_part = (float*)(ws + WS_CNTP);

    // zero lbias64 (2 KB) + ref_cnt (adjacent) in one memset
    hipMemsetAsync(ws + WS_LB64, 0, (WS_CNT - WS_LB64) + 64, stream);

    k_prep<<<512, 256, 0, stream>>>(Wg, Wc, cond, wcomb32, bswH, bswL, lbias64, out);
    k_main<<<NTOK / MT, 256, 0, stream>>>(x, bswH, bswL, lbias64, out, ref_cnt, ref_list,
                                          imp_part, cnt_part);
    k_stats<<<2, 256, 0, stream>>>(imp_part, cnt_part, out);
    k_refine<<<256, 256, 0, stream>>>(x, wcomb32, lbias64, ref_cnt, ref_list, out);
}

// Round 10
// 311.568 us; speedup vs baseline: 1.0947x; 1.0947x over previous
//
#include <hip/hip_runtime.h>
#include <math.h>

#define B_    4
#define T_    8192
#define C_    1024
#define E_    64
#define NTOK  (B_*T_)          // 32768
#define KSEL  2

// d_out offsets (in floats): idx, scores, probs, importance, load
#define OFF_IDX    0
#define OFF_SCORES (NTOK*KSEL)               // 65536
#define OFF_PROBS  (2*NTOK*KSEL)             // 131072
#define OFF_IMP    (OFF_PROBS + NTOK*E_)     // 2228224
#define OFF_LOAD   (OFF_IMP + E_)            // 2228288

// workspace offsets (bytes)
#define WS_W32    0                          // 1024*64*4 = 256 KB ([d][e], refine)
#define WS_BSWH   262144                     // 128 KB bf16 hi, MFMA-frag order
#define WS_BSWL   393216                     // 128 KB bf16 lo
#define WS_LB64   524288                     // 4*64*8 = 2 KB  (zeroed w/ CNT)
#define WS_CNT    526336                     // 4
#define WS_LIST   526400                     // REFINE_CAP*4 = 32 KB

#define REFINE_CAP 8192
#define REFINE_EPS 3e-4f

typedef __attribute__((ext_vector_type(8))) short short8;
typedef __attribute__((ext_vector_type(4))) float f32x4;

// raw workgroup barrier (no vmcnt/lgkm drain), fenced against compiler motion
#define BAR() do { asm volatile("" ::: "memory"); \
                   __builtin_amdgcn_s_barrier();  \
                   asm volatile("" ::: "memory"); } while (0)

// binding global load: compiler CANNOT sink/serialize these (R2 failure mode)
#define GL0(dst, p)    asm volatile("global_load_dwordx4 %0, %1, off" \
                                    : "=v"(dst) : "v"(p) : "memory")

// ---------------------------------------------------------------------------
// K_prep: v9's padding KEPT (wg_s stride 65: store bank = (4a+j+r)&31,
// bijective over (a,r) -> 2 lanes/bank = free, vs 16-way at stride 64;
// read side (c+e)&31 also 2-way). Everything else identical to v8.
// ---------------------------------------------------------------------------
__global__ __launch_bounds__(256) void k_prep(const float* __restrict__ Wg,
                                              const float* __restrict__ Wc,
                                              const float* __restrict__ cond,
                                              float* __restrict__ wcomb32,
                                              short* __restrict__ bswH,
                                              short* __restrict__ bswL,
                                              double* __restrict__ lbias64,
                                              float* __restrict__ out) {
    __shared__ float wg_s[64 * 65];   // [c][e] padded (bank-conflict-free)
    __shared__ float wc_s[64 * 4];    // [c][d_local]
    __shared__ double red[256];

    const int tid = threadIdx.x;
    const int e   = tid & 63;
    const int dg  = tid >> 6;                  // 0..3
    const int d0  = blockIdx.x * 4;

    if (blockIdx.x == 0 && tid < 2 * E_) out[OFF_IMP + tid] = 0.f;

    double ae = 0.0, ao = 0.0;                 // even / odd c chains

    for (int c0 = 0; c0 < C_; c0 += 64) {
        __syncthreads();
#pragma unroll
        for (int k = 0; k < 4; ++k) {
            int li = tid + k * 256;
            int r = li >> 4, c4 = (li & 15) * 4;
            float4 v = *(const float4*)&Wg[(size_t)r * 1024 + c0 + c4];
            wg_s[(c4 + 0) * 65 + r] = v.x;
            wg_s[(c4 + 1) * 65 + r] = v.y;
            wg_s[(c4 + 2) * 65 + r] = v.z;
            wg_s[(c4 + 3) * 65 + r] = v.w;
        }
        if (tid < 128) {
            int cc = tid >> 1, dd0 = (tid & 1) * 2;
            *(float2*)&wc_s[cc * 4 + dd0] =
                *(const float2*)&Wc[(size_t)(c0 + cc) * 2048 + d0 + dd0];
        }
        __syncthreads();
#pragma unroll 8
        for (int c = 0; c < 64; c += 2) {
            ae += (double)wg_s[(c + 0) * 65 + e] * (double)wc_s[(c + 0) * 4 + dg];
            ao += (double)wg_s[(c + 1) * 65 + e] * (double)wc_s[(c + 1) * 4 + dg];
        }
    }
    const double acc = ae + ao;

    if (d0 < 1024) {
        const int d = d0 + dg;
        const int et = e >> 4, nn = e & 15;
        float f = (float)acc;
        wcomb32[d * 64 + e] = f;
        unsigned u = __float_as_uint(f);
        short hi = (short)(u >> 16);
        float r = f - __uint_as_float(u & 0xFFFF0000u);
        short lo = (short)(__float_as_uint(r) >> 16);
        int kchunk = d >> 5, qsel = (d >> 3) & 3, j = d & 7;
        int idx = ((kchunk * 4 + et) * 64 + qsel * 16 + nn) * 8 + j;
        bswH[idx] = hi;
        bswL[idx] = lo;
    } else {
        const int da = d0 - 1024 + dg;
#pragma unroll
        for (int b = 0; b < 4; ++b) {
            double pb = (double)cond[b * 1024 + da] * acc;
            __syncthreads();
            red[tid] = pb;
            __syncthreads();
            if (tid < 64) {
                double s = red[tid] + red[tid + 64] + red[tid + 128] + red[tid + 192];
#if __has_builtin(__builtin_amdgcn_global_atomic_fadd_f64)
                unsafeAtomicAdd(&lbias64[b * 64 + tid], s);
#else
                atomicAdd(&lbias64[b * 64 + tid], s);
#endif
            }
        }
    }
}

// ---------------------------------------------------------------------------
// split 8 consecutive fp32 into bf16 hi + lo
// ---------------------------------------------------------------------------
__device__ __forceinline__ void split8(const float* xv, short8& h, short8& l) {
#pragma unroll
    for (int j = 0; j < 8; ++j) {
        unsigned u = __float_as_uint(xv[j]);
        h[j] = (short)(u >> 16);
        float r = xv[j] - __uint_as_float(u & 0xFFFF0000u);
        l[j] = (short)(__float_as_uint(r) >> 16);
    }
}

// ---------------------------------------------------------------------------
// K_main v10 = v8 EXACTLY (revert of v9's partials/k_stats experiment, which
// regressed ~15 us). B-amortized expert-quarter waves (zero B duplication,
// 64-token amortization), DMA + XOR-swizzled double-buffered A staging,
// binding asm B batch, one counted vmcnt per tile, in-LDS counts + per-block
// global atomics for importance/load (measured cheaper than the partial-store
// + reduce alternative). 512 blocks x 256 thr, 2 blocks/CU, 64 KB LDS.
// A/B frag: [m|n=lane&15][k=(lane>>4)*8+j]; C/D: col=lane&15, row=(lane>>4)*4+r.
// ---------------------------------------------------------------------------
#define MT    64
#define ROWP  65          // epilogue logits row stride (aliases buf0)

__device__ __forceinline__ void stage_tile(const float* __restrict__ x,
                                           float* xs, int token0, int t,
                                           int buf, int wid, int lane) {
#pragma unroll
    for (int p = 0; p < 8; ++p) {
        const int sbase = p * 256 + wid * 64;      // wave-uniform 16B-slot base
        const int s  = sbase + lane;
        const int r  = s >> 5;                     // row 0..63
        const int f  = (s & 31) ^ (r & 7);         // logical 16B granule
        const float* g = &x[(size_t)(token0 + r) * 1024 + t * 128 + f * 4];
        float* l = xs + buf * 8192 + sbase * 4;    // linear dest; HW adds lane*16B
        __builtin_amdgcn_global_load_lds(
            (const __attribute__((address_space(1))) unsigned int*)g,
            (__attribute__((address_space(3))) unsigned int*)l, 16, 0, 0);
    }
}

__global__ __launch_bounds__(256, 2) void k_main(const float* __restrict__ x,
                                                 const short* __restrict__ bswH,
                                                 const short* __restrict__ bswL,
                                                 const double* __restrict__ lbias64,
                                                 float* __restrict__ out,
                                                 unsigned int* __restrict__ ref_cnt,
                                                 int* __restrict__ ref_list) {
    __shared__ __align__(16) float xs[2 * 8192];  // 64 KB: 2 tile buffers; buf0 reused as logits
    __shared__ float invs[MT];
    __shared__ unsigned int cnts[E_];

    const int tid    = threadIdx.x;
    const int wid    = tid >> 6;                  // = expert quarter (et)
    const int lane   = tid & 63;
    const int nn     = lane & 15;
    const int qsel   = lane >> 4;
    const int token0 = blockIdx.x * MT;
    const int b      = token0 >> 13;              // /8192

    if (tid < E_) cnts[tid] = 0;

    f32x4 acc[4];                                 // 4 token-groups x 16 experts
#pragma unroll
    for (int g = 0; g < 4; ++g) acc[g] = (f32x4){0.f, 0.f, 0.f, 0.f};

    // byte base of this wave's B fragments: slab (kchunk*4 + wid), lane*16 B
    const char* bh0 = (const char*)bswH + (size_t)wid * 1024 + lane * 16;
    const char* bl0 = (const char*)bswL + (size_t)wid * 1024 + lane * 16;

    // ---- prologue: stage tile 0 ----
    stage_tile(x, xs, token0, 0, 0, wid, lane);

    for (int t = 0; t < 8; ++t) {                 // K-tiles of 128
        const int cur = t & 1;

        // ---- binding B batch: this wave's 8 fragments of tile t ----
        short8 Bh[4], Bl[4];
        {
            const char* ph = bh0 + (size_t)t * 16384;
            const char* pl = bl0 + (size_t)t * 16384;
#pragma unroll
            for (int kc = 0; kc < 4; ++kc) {
                GL0(Bh[kc], ph + kc * 4096);
                GL0(Bl[kc], pl + kc * 4096);
            }
        }
        // ---- issue next A-tile DMA (flies across compute of t) ----
        if (t < 7) stage_tile(x, xs, token0, t + 1, cur ^ 1, wid, lane);
        // ---- wait: B(t)[8] + stage(t)[8] done; stage(t+1)[8] in flight ----
        if (t < 7) asm volatile("s_waitcnt vmcnt(8)" ::: "memory");
        else       asm volatile("s_waitcnt vmcnt(0)" ::: "memory");
        __builtin_amdgcn_sched_barrier(0);        // rule #18: nothing crosses the wait
        BAR();                                     // all waves' tile-t A landed

        // ---- compute: 4 kc x 4 token-groups, B reused across 64 tokens ----
        const float* abase = xs + cur * 8192;
#pragma unroll
        for (int kc = 0; kc < 4; ++kc) {
            const int f0 = kc * 8 + qsel * 2;
            short8 ah[4], al[4];
#pragma unroll
            for (int g = 0; g < 4; ++g) {
                const int rr = g * 16 + nn;
                const int rx = rr & 7;
                float xv[8];
                *(f32x4*)&xv[0] = *(const f32x4*)(abase + rr * 128 + (((f0    ) ^ rx) << 2));
                *(f32x4*)&xv[4] = *(const f32x4*)(abase + rr * 128 + (((f0 + 1) ^ rx) << 2));
                split8(xv, ah[g], al[g]);
            }
#pragma unroll
            for (int g = 0; g < 4; ++g) {
                acc[g] = __builtin_amdgcn_mfma_f32_16x16x32_bf16(ah[g], Bh[kc], acc[g], 0, 0, 0);
                acc[g] = __builtin_amdgcn_mfma_f32_16x16x32_bf16(ah[g], Bl[kc], acc[g], 0, 0, 0);
                acc[g] = __builtin_amdgcn_mfma_f32_16x16x32_bf16(al[g], Bh[kc], acc[g], 0, 0, 0);
            }
        }
        BAR();                                     // all waves done reading buf[cur]
    }

    // ---- epilogue: logits into xs[tok][e] (stride ROWP, aliases buf0) ----
    const int q4 = qsel * 4;
    {
        float lb = (float)lbias64[b * 64 + wid * 16 + nn];
#pragma unroll
        for (int g = 0; g < 4; ++g) {
#pragma unroll
            for (int r = 0; r < 4; ++r) {
                int tok = g * 16 + q4 + r;
                xs[tok * ROWP + wid * 16 + nn] = acc[g][r] + lb;
            }
        }
    }
    __syncthreads();

    if (tid < MT) {
        const int tk = tid;
        const int base = tk * ROWP;
        float v1 = -1e30f, v2 = -1e30f, v3 = -1e30f;
        int i1 = 0, i2 = 0;
        for (int e = 0; e < E_; ++e) {
            float l = xs[base + e];
            if (l > v1)      { v3 = v2; v2 = v1; i2 = i1; v1 = l; i1 = e; }
            else if (l > v2) { v3 = v2; v2 = l; i2 = e; }
            else if (l > v3) { v3 = l; }
        }
        float sum = 0.f;
        for (int e = 0; e < E_; ++e) {
            float ex = __expf(xs[base + e] - v1);
            xs[base + e] = ex;
            sum += ex;
        }
        invs[tk] = 1.0f / sum;

        const int gt = token0 + tk;
        float s1 = 1.0f / (1.0f + __expf(v2 - v1));   // softmax over top-2
        *(float2*)&out[OFF_IDX + (size_t)gt * 2]    = make_float2((float)i1, (float)i2);
        *(float2*)&out[OFF_SCORES + (size_t)gt * 2] = make_float2(s1, 1.0f - s1);
        atomicAdd(&cnts[i1], 1u);
        atomicAdd(&cnts[i2], 1u);

        float g12 = v1 - v2, g23 = v2 - v3;
        float g = g12 < g23 ? g12 : g23;
        if (g < REFINE_EPS) {
            unsigned int pos = atomicAdd(ref_cnt, 1u);
            if (pos < REFINE_CAP) ref_list[pos] = gt;
        }
    }
    __syncthreads();

    // probs: 4096 floats = 1024 float4, coalesced (4 per thread)
    float* probs = out + OFF_PROBS + (size_t)token0 * E_;
#pragma unroll
    for (int k = 0; k < 4; ++k) {
        int li4 = tid + k * 256;
        int tok = li4 >> 4;
        int c4 = (li4 & 15) << 2;
        float inv = invs[tok];
        int o = tok * ROWP + c4;
        *(float4*)&probs[(size_t)li4 * 4] =
            make_float4(xs[o] * inv, xs[o + 1] * inv,
                        xs[o + 2] * inv, xs[o + 3] * inv);
    }

    // importance + load: one atomic each per e per block (measured best)
    if (tid < E_) {
        const int e = tid;
        float s = 0.f;
        for (int tt = 0; tt < MT; ++tt) s += xs[tt * ROWP + e] * invs[tt];
        atomicAdd(&out[OFF_IMP + e],  s * (1.0f / (float)NTOK));
        atomicAdd(&out[OFF_LOAD + e], (float)cnts[e] * (1.0f / (float)(NTOK * KSEL)));
    }
}

// ---------------------------------------------------------------------------
// K_ref: UNCHANGED. fp64 re-evaluation of ambiguous tokens, one wave/token.
// ---------------------------------------------------------------------------
__global__ __launch_bounds__(256) void k_refine(const float* __restrict__ x,
                                                const float* __restrict__ wcomb32,
                                                const double* __restrict__ lbias64,
                                                const unsigned int* __restrict__ ref_cnt,
                                                const int* __restrict__ ref_list,
                                                float* __restrict__ out) {
    int wave = (int)((blockIdx.x * blockDim.x + threadIdx.x) >> 6);
    int lane = threadIdx.x & 63;
    unsigned int n = *ref_cnt;
    if (n > REFINE_CAP) n = REFINE_CAP;
    const int nwaves = (int)((gridDim.x * blockDim.x) >> 6);

    for (unsigned int wi = wave; wi < n; wi += nwaves) {
        const int gt = ref_list[wi];
        const int b = gt / T_;
        const float* xrow = x + (size_t)gt * C_;
        double a0 = 0.0, a1 = 0.0, a2 = 0.0, a3 = 0.0;
        for (int d = 0; d < C_; d += 4) {
            a0 += (double)xrow[d + 0] * (double)wcomb32[(d + 0) * 64 + lane];
            a1 += (double)xrow[d + 1] * (double)wcomb32[(d + 1) * 64 + lane];
            a2 += (double)xrow[d + 2] * (double)wcomb32[(d + 2) * 64 + lane];
            a3 += (double)xrow[d + 3] * (double)wcomb32[(d + 3) * 64 + lane];
        }
        double acc = ((a0 + a1) + (a2 + a3)) + lbias64[b * 64 + lane];

        double v = acc; int id = lane;
        for (int off = 32; off > 0; off >>= 1) {
            double ov = __shfl_xor(v, off, 64);
            int oid   = __shfl_xor(id, off, 64);
            if (ov > v || (ov == v && oid < id)) { v = ov; id = oid; }
        }
        double v1 = v; int i1 = id;
        v = (lane == i1) ? -1e300 : acc; id = lane;
        for (int off = 32; off > 0; off >>= 1) {
            double ov = __shfl_xor(v, off, 64);
            int oid   = __shfl_xor(id, off, 64);
            if (ov > v || (ov == v && oid < id)) { v = ov; id = oid; }
        }
        double v2 = v; int i2 = id;

        if (lane == 0) {
            float s1 = (float)(1.0 / (1.0 + exp(v2 - v1)));
            *(float2*)&out[OFF_IDX + (size_t)gt * 2]    = make_float2((float)i1, (float)i2);
            *(float2*)&out[OFF_SCORES + (size_t)gt * 2] = make_float2(s1, 1.0f - s1);
        }
    }
}

// ---------------------------------------------------------------------------
extern "C" void kernel_launch(void* const* d_in, const int* in_sizes, int n_in,
                              void* d_out, int out_size, void* d_ws, size_t ws_size,
                              hipStream_t stream) {
    const float* x    = (const float*)d_in[0];   // (4,8192,1024)
    const float* cond = (const float*)d_in[1];   // (4,1024)
    const float* Wg   = (const float*)d_in[2];   // (64,1024)
    const float* Wc   = (const float*)d_in[3];   // (1024,2048)
    float* out = (float*)d_out;
    char*  ws  = (char*)d_ws;

    float*  wcomb32 = (float*)(ws + WS_W32);
    short*  bswH    = (short*)(ws + WS_BSWH);
    short*  bswL    = (short*)(ws + WS_BSWL);
    double* lbias64 = (double*)(ws + WS_LB64);
    unsigned int* ref_cnt = (unsigned int*)(ws + WS_CNT);
    int*    ref_list = (int*)(ws + WS_LIST);

    // zero lbias64 (2 KB) + ref_cnt (adjacent) in one memset
    hipMemsetAsync(ws + WS_LB64, 0, (WS_CNT - WS_LB64) + 64, stream);

    k_prep<<<512, 256, 0, stream>>>(Wg, Wc, cond, wcomb32, bswH, bswL, lbias64, out);
    k_main<<<NTOK / MT, 256, 0, stream>>>(x, bswH, bswL, lbias64, out, ref_cnt, ref_list);
    k_refine<<<256, 256, 0, stream>>>(x, wcomb32, lbias64, ref_cnt, ref_list, out);
}